// Round 3
// baseline (104.026 us; speedup 1.0000x reference)
//
#include <hip/hip_runtime.h>
#include <hip/hip_fp16.h>

// MinEuclideanDistBlock: out[b,n] = min_w sum_c sqrt(max(||win||^2+||shp||^2-2*cross,0))
// B=64,C=3,L=2048,N=256,S=64,W=1985.
// R3: prep kernel precomputes (to d_ws): 8 shifted bf16 copies of x (per b,c),
// fp16 -0.5*window-norms, bf16 shapelets + -0.5*norms; inits out to +inf.
// Main: grid 2048 = 64b x 8nt(32n) x 4wh(512w); 4 waves; wave tile 32w x 32n.
// A-frags = single aligned ds_read_b128 from shifted copies (stride 150 u64 ->
// word skew 12 mod 32 -> 5-phase optimal). B-frags per-lane from global (L2).
// acc init = hw + hs (both pre-scaled -0.5) so acc=-d2/2; d=sqrt2*sqrt(max(-acc,0)).

typedef float  v4f __attribute__((ext_vector_type(4)));
typedef unsigned int v4u __attribute__((ext_vector_type(4)));
typedef short  v8s __attribute__((ext_vector_type(8)));
typedef unsigned short u16;
typedef unsigned int   u32;
typedef unsigned long long u64;

#define N_ 256
#define C_ 3
#define L_ 2048
#define W_ 1985
#define XPAD 2176          // elements per shifted copy in global (zero-padded)
#define CPY_U64 150        // u64 per LDS copy (600 elems; word stride 300 = 12 mod 32)
#define WL 512             // w-range per block

// d_ws byte offsets
#define OFF_GX   0u               // [64][3][8][XPAD] u16          = 6,684,672 B
#define OFF_HW   6684672u         // [64][3][2048] half            =   786,432 B
#define OFF_SHP  7471104u         // [3][256][64] u16 (bf16)       =    98,304 B
#define OFF_HS   7569408u         // [3][256] f32 (-0.5*norm)      =     3,072 B

__device__ __forceinline__ u16 f2bf(float f) {
    u32 u = __builtin_bit_cast(u32, f);
    return (u16)((u + 0x7FFFu + ((u >> 16) & 1u)) >> 16);
}
__device__ __forceinline__ float bf2f(u16 b) {
    return __builtin_bit_cast(float, ((u32)b) << 16);
}
__device__ __forceinline__ u64 pack4(v4f v) {
    return (u64)f2bf(v[0]) | ((u64)f2bf(v[1]) << 16)
         | ((u64)f2bf(v[2]) << 32) | ((u64)f2bf(v[3]) << 48);
}

//============================ PREP ============================
// blocks 0..191: (b,c) x-task; 192..194: shapelet task; 195..258: out init.
__global__ __launch_bounds__(256)
void prep_kernel(const float* __restrict__ x, const float* __restrict__ shp,
                 u16* __restrict__ gx, u16* __restrict__ ghw,
                 u16* __restrict__ gshp, float* __restrict__ ghs,
                 u32* __restrict__ out_u)
{
    const int blk = blockIdx.x, tid = threadIdx.x;
    if (blk < 192) {
        __shared__ u16 xb[2240];                 // bf16 row + 192 zero pad
        const int b = blk / 3, c = blk % 3;
        const float* xr = x + (size_t)(b * 3 + c) * L_;
        {
            v4f a0 = *(const v4f*)(xr + tid * 8);
            v4f a1 = *(const v4f*)(xr + tid * 8 + 4);
            ((u64*)xb)[tid * 2]     = pack4(a0);
            ((u64*)xb)[tid * 2 + 1] = pack4(a1);
            if (tid < 24) ((u64*)xb)[512 + tid] = 0;
        }
        __syncthreads();
        // 8 shifted copies: copy r, 16B unit u covers x elems [8u+r, 8u+r+7]
        {
            const int r = tid >> 5, u0 = tid & 31;
            const bool odd = (r & 1);
            const int wadd = r >> 1;
            u16* grow = gx + ((size_t)(b * 3 + c) * 8 + r) * XPAD;
            const u32* lw = (const u32*)xb;
            #pragma unroll 1
            for (int i = 0; i < 9; ++i) {
                int u = u0 + i * 32;
                if (u < 272) {
                    u32 w[5];
                    #pragma unroll
                    for (int j = 0; j < 5; ++j) w[j] = lw[u * 4 + wadd + j];
                    v4u o;
                    #pragma unroll
                    for (int j = 0; j < 4; ++j) {
                        u32 sh = (w[j] >> 16) | (w[j + 1] << 16);
                        o[j] = odd ? sh : w[j];
                    }
                    *(v4u*)(grow + u * 8) = o;
                }
            }
        }
        // sliding -0.5*||win||^2 (from bf16-rounded values), fp16, 8 per thread
        {
            float e[80];
            #pragma unroll
            for (int j = 0; j < 20; ++j) {
                u64 ch = ((const u64*)xb)[tid * 2 + j];
                e[j * 4 + 0] = bf2f((u16)(ch));
                e[j * 4 + 1] = bf2f((u16)(ch >> 16));
                e[j * 4 + 2] = bf2f((u16)(ch >> 32));
                e[j * 4 + 3] = bf2f((u16)(ch >> 48));
            }
            float s = 0.f;
            #pragma unroll
            for (int i = 0; i < 64; ++i) s += e[i] * e[i];
            union { v4u v; __half h[8]; } hp;
            hp.h[0] = __float2half(-0.5f * s);
            #pragma unroll
            for (int k = 1; k < 8; ++k) {
                s += e[63 + k] * e[63 + k] - e[k - 1] * e[k - 1];
                hp.h[k] = __float2half(-0.5f * s);
            }
            *(v4u*)(ghw + (size_t)(b * 3 + c) * L_ + tid * 8) = hp.v;
        }
    } else if (blk < 195) {
        const int c = blk - 192;
        const int n = tid;
        const float* row = shp + ((size_t)c * N_ + n) * 64;
        float sacc = 0.f;
        #pragma unroll
        for (int k = 0; k < 8; ++k) {
            v4f a0 = *(const v4f*)(row + k * 8);
            v4f a1 = *(const v4f*)(row + k * 8 + 4);
            u64 p0 = pack4(a0), p1 = pack4(a1);
            union { u64 u[2]; v4u v; } st; st.u[0] = p0; st.u[1] = p1;
            *(v4u*)(gshp + ((size_t)c * N_ + n) * 64 + k * 8) = st.v;
            #pragma unroll
            for (int j = 0; j < 4; ++j) {
                float e0 = bf2f((u16)(p0 >> (16 * j)));
                float e1 = bf2f((u16)(p1 >> (16 * j)));
                sacc += e0 * e0 + e1 * e1;
            }
        }
        ghs[c * N_ + n] = -0.5f * sacc;
    } else {
        int i = (blk - 195) * 256 + tid;     // exactly 16384
        out_u[i] = 0x7F800000u;              // +inf
    }
}

//============================ MAIN ============================
__global__ __launch_bounds__(256, 4)
void shapelet_min_kernel(const u16* __restrict__ gx, const u16* __restrict__ ghw,
                         const u16* __restrict__ gshp, const float* __restrict__ ghs,
                         u32* __restrict__ out_u)
{
    __shared__ __align__(16) u64 xcopy[C_ * 8 * CPY_U64];  // 28800 B
    __shared__ __align__(16) __half hwq[C_ * WL];          //  3072 B
    __shared__ float red[4][32];

    const int tid  = threadIdx.x;
    const int wave = tid >> 6;
    const int lane = tid & 63;
    const int m    = lane & 15;
    const int q    = lane >> 4;
    const int r    = m & 7;         // which shifted copy
    const int a    = m >> 3;
    const int wh   = blockIdx.x & 3;
    const int nb   = (blockIdx.x >> 2) & 7;
    const int b    = blockIdx.x >> 5;
    const int n0   = nb << 5;
    const int wstart = wh * WL;

    // stage x copies: 24 rows x 75 16B-units = 1800 units
    {
        const u16* gxb = gx + (size_t)b * 24 * XPAD;
        #pragma unroll
        for (int i = 0; i < 8; ++i) {
            int idx = tid + (i << 8);
            if (idx < 1800) {
                int cr = idx / 75;
                int u  = idx - cr * 75;
                v4u v = *(const v4u*)(gxb + cr * XPAD + wstart + u * 8);
                *(v4u*)((char*)xcopy + cr * 1200 + u * 16) = v;
            }
        }
    }
    // stage hw: 3c x 64 16B-units
    if (tid < 192) {
        int c = tid >> 6, u = tid & 63;
        v4u v = *(const v4u*)(ghw + (size_t)(b * 3 + c) * L_ + wstart + u * 8);
        *(v4u*)((char*)hwq + c * 1024 + u * 16) = v;
    }
    // B fragments + hs straight from global (L1/L2-resident)
    v8s bfr[C_][2][2];
    float hs[C_][2];
    #pragma unroll
    for (int c = 0; c < C_; ++c)
        #pragma unroll
        for (int nt = 0; nt < 2; ++nt) {
            int n = n0 + nt * 16 + m;
            hs[c][nt] = ghs[c * N_ + n];
            #pragma unroll
            for (int h = 0; h < 2; ++h)
                bfr[c][nt][h] = *(const v8s*)(gshp + ((size_t)(c * N_ + n) * 64 + h * 32 + q * 8));
        }
    __syncthreads();

    float mins[2] = {1e30f, 1e30f};
    const int laneoff = q + a;

    #pragma unroll 1
    for (int it = 0; it < 4; ++it) {
        const int wb = it * 128 + wave * 32;
        if (wstart + wb >= W_) continue;      // wave-uniform skip (only wh3/it3/wave3)

        float sums[2][2][4];
        #pragma unroll
        for (int mt = 0; mt < 2; ++mt)
            #pragma unroll
            for (int nt = 0; nt < 2; ++nt)
                #pragma unroll
                for (int g = 0; g < 4; ++g) sums[mt][nt][g] = 0.f;

        #pragma unroll
        for (int c = 0; c < C_; ++c) {
            v4f acc[2][2];
            #pragma unroll
            for (int mt = 0; mt < 2; ++mt) {
                union { u64 u; __half h4[4]; } wq;
                wq.u = *(const u64*)&hwq[c * WL + wb + mt * 16 + q * 4];
                #pragma unroll
                for (int g = 0; g < 4; ++g) {
                    float hv = __half2float(wq.h4[g]);
                    acc[mt][0][g] = hv + hs[c][0];
                    acc[mt][1][g] = hv + hs[c][1];
                }
            }
            const char* cb = (const char*)xcopy + (c * 8 + r) * 1200;
            #pragma unroll
            for (int h = 0; h < 2; ++h) {
                v8s afr[2];
                #pragma unroll
                for (int mt = 0; mt < 2; ++mt) {
                    int k = (wb >> 3) + mt * 2 + h * 4 + laneoff;
                    afr[mt] = *(const v8s*)(cb + k * 16);   // aligned b128, 5-phase
                }
                #pragma unroll
                for (int mt = 0; mt < 2; ++mt)
                    #pragma unroll
                    for (int nt = 0; nt < 2; ++nt)
                        acc[mt][nt] = __builtin_amdgcn_mfma_f32_16x16x32_bf16(
                            afr[mt], bfr[c][nt][h], acc[mt][nt], 0, 0, 0);
            }
            #pragma unroll
            for (int mt = 0; mt < 2; ++mt)
                #pragma unroll
                for (int nt = 0; nt < 2; ++nt)
                    #pragma unroll
                    for (int g = 0; g < 4; ++g)
                        sums[mt][nt][g] += __builtin_amdgcn_sqrtf(fmaxf(-acc[mt][nt][g], 0.f));
        }
        #pragma unroll
        for (int mt = 0; mt < 2; ++mt) {
            #pragma unroll
            for (int g = 0; g < 4; ++g) {
                bool ok = (wstart + wb + mt * 16 + q * 4 + g) < W_;
                #pragma unroll
                for (int nt = 0; nt < 2; ++nt) {
                    float vv = ok ? sums[mt][nt][g] : 1e30f;
                    mins[nt] = fminf(mins[nt], vv);
                }
            }
        }
    }

    #pragma unroll
    for (int nt = 0; nt < 2; ++nt) {
        mins[nt] = fminf(mins[nt], __shfl_xor(mins[nt], 16));
        mins[nt] = fminf(mins[nt], __shfl_xor(mins[nt], 32));
    }
    if (lane < 16) { red[wave][m] = mins[0]; red[wave][16 + m] = mins[1]; }
    __syncthreads();
    if (tid < 32) {
        float v = fminf(fminf(red[0][tid], red[1][tid]),
                        fminf(red[2][tid], red[3][tid]));
        atomicMin(out_u + (size_t)b * N_ + n0 + tid,
                  __float_as_uint(v * 1.41421356237f));
    }
}

extern "C" void kernel_launch(void* const* d_in, const int* in_sizes, int n_in,
                              void* d_out, int out_size, void* d_ws, size_t ws_size,
                              hipStream_t stream) {
    const float* x   = (const float*)d_in[0];   // (64, 3, 2048) fp32
    const float* shp = (const float*)d_in[1];   // (3, 256, 64) fp32
    u32* out_u       = (u32*)d_out;             // (64, 1, 256) fp32 via u32 atomicMin

    char* ws = (char*)d_ws;
    u16*   gx   = (u16*)(ws + OFF_GX);
    u16*   ghw  = (u16*)(ws + OFF_HW);
    u16*   gshp = (u16*)(ws + OFF_SHP);
    float* ghs  = (float*)(ws + OFF_HS);

    hipLaunchKernelGGL(prep_kernel, dim3(259), dim3(256), 0, stream,
                       x, shp, gx, ghw, gshp, ghs, out_u);
    hipLaunchKernelGGL(shapelet_min_kernel, dim3(2048), dim3(256), 0, stream,
                       gx, ghw, gshp, ghs, out_u);
}